// Round 1
// baseline (936.540 us; speedup 1.0000x reference)
//
#include <hip/hip_runtime.h>
#include <math.h>

// Problem constants
#define KCODES 1024
#define DDIM   64
constexpr int NROWS = 16 * 64 * 64;   // 65536 rows (B*H*W)

// Output layout (floats), concatenated in reference return order:
// z_q_out [16,64,64,64], idx_out [16,64,64], emb_new [64,1024],
// emb_ema_new [64,1024], counts_ema_new [1024]
constexpr size_t O_ZQ  = 0;
constexpr size_t O_IDX = 4194304;
constexpr size_t O_EMB = O_IDX + 65536;   // 4259840
constexpr size_t O_EMA = O_EMB + 65536;   // 4325376
constexpr size_t O_CEN = O_EMA + 65536;   // 4390912

// Workspace layout (float offsets)
constexpr size_t W_UPD   = 0;              // [K][D] segment-sum accumulator (zeroed)
constexpr size_t W_CNT   = 65536;          // [K] histogram (zeroed)
constexpr size_t W_ENORM = W_CNT + 1024;   // [K] ||e_k||^2
constexpr size_t W_EMBT  = W_ENORM + 1024; // [K][D] transposed codebook

// ---------------------------------------------------------------------------
// K1: build embT (row-major per code) and eNorm.
__global__ __launch_bounds__(256) void vq_prep(const float* __restrict__ emb,
                                               float* __restrict__ ws) {
  const int i = blockIdx.x * 256 + threadIdx.x;   // 0..65535
  const int k = i >> 6;
  const int d = i & 63;
  ws[W_EMBT + i] = emb[d * KCODES + k];
  if (i < KCODES) {
    float s = 0.f;
    #pragma unroll
    for (int dd = 0; dd < DDIM; ++dd) {
      const float v = emb[dd * KCODES + i];
      s = fmaf(v, v, s);
    }
    ws[W_ENORM + i] = s;
  }
}

// ---------------------------------------------------------------------------
// K2: per-row argmin over codes + fused epilogue.
// Block = 256 threads: tid 0-127 (waves 0,1) scan codes [0,512),
// tid 128-255 (waves 2,3) scan codes [512,1024) for the SAME 128 rows.
// k is wave-uniform -> codebook loads scalarize to s_load (SGPR operands).
__global__ __launch_bounds__(256, 2) void vq_main(const float* __restrict__ z_e,
                                                  const float* __restrict__ emb,
                                                  float* ws,
                                                  float* __restrict__ out) {
  const int tid   = threadIdx.x;
  const int split = tid >> 7;       // 0 or 1 (whole waves share a split)
  const int r     = tid & 127;
  const int n     = blockIdx.x * 128 + r;           // row id in [0, 65536)

  // z_e[b][d][h][w]; row n = (b, h, w)
  const int b  = n >> 12;
  const int hw = n & 4095;
  const size_t zbase = (size_t)b * 262144 + (size_t)hw;  // + d*4096

  float z[DDIM];
  #pragma unroll
  for (int d = 0; d < DDIM; ++d) z[d] = z_e[zbase + (size_t)d * 4096];

  const float* __restrict__ eN = ws + W_ENORM;

  float minval = INFINITY;
  int   minidx = 0;
  const int k0 = split * 512;

  for (int kk = 0; kk < 512; kk += 8) {
    float acc[8] = {0.f, 0.f, 0.f, 0.f, 0.f, 0.f, 0.f, 0.f};
    #pragma unroll
    for (int d = 0; d < DDIM; ++d) {
      const float zd = z[d];
      const int base = d * KCODES + k0 + kk;
      #pragma unroll
      for (int j = 0; j < 8; ++j)
        acc[j] = fmaf(zd, emb[base + j], acc[j]);
    }
    #pragma unroll
    for (int j = 0; j < 8; ++j) {
      // dist (minus per-row const ||z||^2): ||e||^2 - 2 z.e
      const float val = fmaf(-2.f, acc[j], eN[k0 + kk + j]);
      if (val < minval) { minval = val; minidx = k0 + kk + j; }  // first-min tie-break
    }
  }

  // merge the two K-splits (split 1 has strictly larger indices: strict < keeps
  // the first occurrence semantics of jnp.argmin)
  __shared__ float s_val[128];
  __shared__ int   s_idx[128];
  if (split == 1) { s_val[r] = minval; s_idx[r] = minidx; }
  __syncthreads();

  if (split == 0) {
    const float v1 = s_val[r];
    if (v1 < minval) { minval = v1; minidx = s_idx[r]; }

    // idx output (as float; harness reads whole buffer as f32)
    out[O_IDX + n] = (float)minidx;

    // histogram
    atomicAdd(ws + W_CNT + minidx, 1.0f);

    // z_q = z + (e - z)  (match reference fp ops), and segment-sum scatter
    const float4* __restrict__ er4 =
        (const float4*)(ws + W_EMBT + (size_t)minidx * 64);
    float* upd = ws + W_UPD + (size_t)minidx * 64;
    #pragma unroll
    for (int t = 0; t < 16; ++t) {
      const float4 e4 = er4[t];
      const int d = 4 * t;
      const float e0 = e4.x, e1 = e4.y, e2 = e4.z, e3 = e4.w;
      out[O_ZQ + zbase + (size_t)(d + 0) * 4096] = z[d + 0] + (e0 - z[d + 0]);
      out[O_ZQ + zbase + (size_t)(d + 1) * 4096] = z[d + 1] + (e1 - z[d + 1]);
      out[O_ZQ + zbase + (size_t)(d + 2) * 4096] = z[d + 2] + (e2 - z[d + 2]);
      out[O_ZQ + zbase + (size_t)(d + 3) * 4096] = z[d + 3] + (e3 - z[d + 3]);
      atomicAdd(upd + d + 0, z[d + 0]);
      atomicAdd(upd + d + 1, z[d + 1]);
      atomicAdd(upd + d + 2, z[d + 2]);
      atomicAdd(upd + d + 3, z[d + 3]);
    }
  }
}

// ---------------------------------------------------------------------------
// K3: EMA updates + normalization. Each block redundantly reduces n.
__global__ __launch_bounds__(256) void vq_final(const float* __restrict__ emb_ema,
                                                const float* __restrict__ counts_ema,
                                                const float* __restrict__ ws,
                                                float* __restrict__ out) {
  __shared__ float red[256];
  const int tid = threadIdx.x;
  const float* cnt = ws + W_CNT;

  float psum = 0.f;
  for (int t = tid; t < KCODES; t += 256) {
    const float ce  = counts_ema[t];
    const float cen = ce + 0.01f * (cnt[t] - ce);
    psum += cen;
    if (blockIdx.x == 0) out[O_CEN + t] = cen;
  }
  red[tid] = psum;
  __syncthreads();
  #pragma unroll
  for (int s = 128; s > 0; s >>= 1) {
    if (tid < s) red[tid] += red[tid + s];
    __syncthreads();
  }
  const float nsum = red[0];

  const int i = blockIdx.x * 256 + tid;   // 0..65535 over [D][K]
  const int d = i >> 10;
  const int k = i & 1023;

  const float ce  = counts_ema[k];
  const float cen = ce + 0.01f * (cnt[k] - ce);
  const float norm = (cen + 1e-5f) / (nsum + (float)KCODES * 1e-5f) * nsum;

  const float ema     = emb_ema[i];
  const float ema_new = ema + 0.01f * (ws[W_UPD + (size_t)k * 64 + d] - ema);
  out[O_EMA + i] = ema_new;
  out[O_EMB + i] = ema_new / norm;
}

// ---------------------------------------------------------------------------
extern "C" void kernel_launch(void* const* d_in, const int* in_sizes, int n_in,
                              void* d_out, int out_size, void* d_ws, size_t ws_size,
                              hipStream_t stream) {
  const float* z_e        = (const float*)d_in[0];
  const float* emb        = (const float*)d_in[1];
  const float* emb_ema    = (const float*)d_in[2];
  const float* counts_ema = (const float*)d_in[3];
  float* out = (float*)d_out;
  float* ws  = (float*)d_ws;

  // zero the accumulators (upd [K*D] + counts [K])
  hipMemsetAsync(ws, 0, (KCODES * DDIM + KCODES) * sizeof(float), stream);

  vq_prep<<<256, 256, 0, stream>>>(emb, ws);
  vq_main<<<512, 256, 0, stream>>>(z_e, emb, ws, out);
  vq_final<<<256, 256, 0, stream>>>(emb_ema, counts_ema, ws, out);
}

// Round 2
// 198.913 us; speedup vs baseline: 4.7083x; 4.7083x over previous
//
#include <hip/hip_runtime.h>
#include <math.h>

// Problem constants
#define KCODES 1024
#define DDIM   64
constexpr int NROWS = 16 * 64 * 64;   // 65536 rows (B*H*W)

// Output layout (floats), concatenated in reference return order:
// z_q_out [16,64,64,64], idx_out [16,64,64], emb_new [64,1024],
// emb_ema_new [64,1024], counts_ema_new [1024]
constexpr size_t O_ZQ  = 0;
constexpr size_t O_IDX = 4194304;
constexpr size_t O_EMB = O_IDX + 65536;   // 4259840
constexpr size_t O_EMA = O_EMB + 65536;   // 4325376
constexpr size_t O_CEN = O_EMA + 65536;   // 4390912

// Workspace layout (float offsets)
constexpr size_t W_UPD   = 0;              // [K][D] segment-sum accumulator (zeroed)
constexpr size_t W_CNT   = 65536;          // [K] histogram (zeroed)
constexpr size_t W_ENORM = W_CNT + 1024;   // [K] ||e_k||^2
constexpr size_t W_EMBT  = W_ENORM + 1024; // [K][D] transposed codebook

// ---------------------------------------------------------------------------
// K1: build embT (row-major per code) and eNorm.
__global__ __launch_bounds__(256) void vq_prep(const float* __restrict__ emb,
                                               float* __restrict__ ws) {
  const int i = blockIdx.x * 256 + threadIdx.x;   // 0..65535
  const int k = i >> 6;
  const int d = i & 63;
  ws[W_EMBT + i] = emb[d * KCODES + k];
  if (i < KCODES) {
    float s = 0.f;
    #pragma unroll
    for (int dd = 0; dd < DDIM; ++dd) {
      const float v = emb[dd * KCODES + i];
      s = fmaf(v, v, s);
    }
    ws[W_ENORM + i] = s;
  }
}

// ---------------------------------------------------------------------------
// K2: LDS-tiled register-blocked distance GEMM + argmin + fused epilogue.
//
// Block: 256 threads = 16 rowgrps x 16 colgrps. Tile: 128 rows (whole K range
// per block) x 256 codes per chunk (4 chunks). Per-thread: 8 rows x 16 codes.
// d is staged in two 32-deep phases so e-tile LDS stays at 32 KB.
// LDS: z 32 KB + e 32 KB = 64 KB -> 2 blocks/CU.
__global__ __launch_bounds__(256, 2) void vq_main(const float* __restrict__ z_e,
                                                  const float* __restrict__ emb,
                                                  float* ws,
                                                  float* __restrict__ out) {
  __shared__ float z_lds[DDIM * 128];   // [d][row]   32 KB
  __shared__ float e_lds[32 * 256];     // [dp][code] 32 KB (reused for reduce)

  const int tid    = threadIdx.x;
  const int rowgrp = tid >> 4;          // 0..15
  const int colgrp = tid & 15;          // 0..15
  const int r0     = rowgrp * 8;        // thread's first row (of 128)
  const int c0t    = colgrp * 16;       // thread's first code within chunk

  const int n0  = blockIdx.x * 128;     // block's first row id
  const int b   = n0 >> 12;
  const int hw0 = n0 & 4095;            // multiple of 128
  // z_e[b][d][hw]; float4 base for this block's rows
  const float4* __restrict__ z4  = (const float4*)z_e;
  const float4* __restrict__ e4g = (const float4*)emb;

  // ---- stage z tile: [64][128] <- z_e[b][d][hw0..hw0+128) ----
  {
    const int zb4 = b * 65536 + (hw0 >> 2);   // float4 index base
    float4* __restrict__ zl4 = (float4*)z_lds;
    #pragma unroll
    for (int it = 0; it < 8; ++it) {
      const int f  = tid + it * 256;          // 0..2047
      const int d  = f >> 5;
      const int rq = f & 31;
      zl4[d * 32 + rq] = z4[zb4 + d * 1024 + rq];
    }
  }

  const float* __restrict__ eN = ws + W_ENORM;

  float minval[8];
  int   minidx[8];
  #pragma unroll
  for (int i = 0; i < 8; ++i) { minval[i] = INFINITY; minidx[i] = 0; }

  for (int chunk = 0; chunk < 4; ++chunk) {
    const int c0 = chunk * 256;

    float acc[8][16];
    #pragma unroll
    for (int i = 0; i < 8; ++i)
      #pragma unroll
      for (int j = 0; j < 16; ++j) acc[i][j] = 0.f;

    for (int phase = 0; phase < 2; ++phase) {
      __syncthreads();   // previous phase's e_lds reads done
      // ---- stage e tile: [32][256] <- emb[phase*32+dp][c0..c0+256) ----
      {
        float4* __restrict__ el4 = (float4*)e_lds;
        #pragma unroll
        for (int it = 0; it < 8; ++it) {
          const int f  = tid + it * 256;      // 0..2047
          const int dp = f >> 6;
          const int kq = f & 63;
          el4[dp * 64 + kq] = e4g[(phase * 32 + dp) * 256 + (c0 >> 2) + kq];
        }
      }
      __syncthreads();

      #pragma unroll 4
      for (int dp = 0; dp < 32; ++dp) {
        const int d = phase * 32 + dp;
        float zf[8], ef[16];
        const float4* zr = (const float4*)(z_lds + d * 128 + r0);
        const float4* er = (const float4*)(e_lds + dp * 256 + c0t);
        float4 za = zr[0], zb = zr[1];
        zf[0]=za.x; zf[1]=za.y; zf[2]=za.z; zf[3]=za.w;
        zf[4]=zb.x; zf[5]=zb.y; zf[6]=zb.z; zf[7]=zb.w;
        #pragma unroll
        for (int q = 0; q < 4; ++q) {
          float4 ev = er[q];
          ef[4*q+0]=ev.x; ef[4*q+1]=ev.y; ef[4*q+2]=ev.z; ef[4*q+3]=ev.w;
        }
        #pragma unroll
        for (int i = 0; i < 8; ++i)
          #pragma unroll
          for (int j = 0; j < 16; ++j)
            acc[i][j] = fmaf(zf[i], ef[j], acc[i][j]);
      }
    }

    // ---- fold this chunk into the running argmin ----
    float en[16];
    {
      const float4* eN4 = (const float4*)(eN + c0 + c0t);
      #pragma unroll
      for (int q = 0; q < 4; ++q) {
        float4 v = eN4[q];
        en[4*q+0]=v.x; en[4*q+1]=v.y; en[4*q+2]=v.z; en[4*q+3]=v.w;
      }
    }
    #pragma unroll
    for (int i = 0; i < 8; ++i) {
      #pragma unroll
      for (int j = 0; j < 16; ++j) {
        const float val = fmaf(-2.f, acc[i][j], en[j]);   // ||e||^2 - 2 z.e
        if (val < minval[i]) { minval[i] = val; minidx[i] = c0 + c0t + j; }
      }
    }
  }

  // ---- cross-colgrp argmin reduction (reuse e_lds) ----
  __syncthreads();
  float* sval = e_lds;                       // [128][17] padded
  int*   sidx = (int*)(e_lds + 2176);        // [128][17]
  int*   bidx = (int*)(e_lds + 4352);        // [128]
  #pragma unroll
  for (int i = 0; i < 8; ++i) {
    sval[(r0 + i) * 17 + colgrp] = minval[i];
    sidx[(r0 + i) * 17 + colgrp] = minidx[i];
  }
  __syncthreads();

  if (tid < 128) {
    const int row = tid;
    float bv = sval[row * 17 + 0];
    int   bi = sidx[row * 17 + 0];
    #pragma unroll
    for (int c = 1; c < 16; ++c) {
      const float v = sval[row * 17 + c];
      const int   ix = sidx[row * 17 + c];
      if (v < bv || (v == bv && ix < bi)) { bv = v; bi = ix; }
    }
    bidx[row] = bi;
    out[O_IDX + n0 + row] = (float)bi;
    atomicAdd(ws + W_CNT + bi, 1.0f);
  }
  __syncthreads();

  // ---- epilogue A: z_q = z + (e - z), coalesced over rows ----
  {
    const int row   = tid & 127;
    const int dhalf = tid >> 7;
    const int code  = bidx[row];
    const float* __restrict__ erow = ws + W_EMBT + (size_t)code * 64;
    const size_t obase = O_ZQ + (size_t)b * 262144 + (size_t)(hw0 + row);
    #pragma unroll
    for (int t = 0; t < 32; ++t) {
      const int d = dhalf * 32 + t;
      const float z = z_lds[d * 128 + row];
      const float e = erow[d];
      out[obase + (size_t)d * 4096] = z + (e - z);
    }
  }

  // ---- epilogue B: segment-sum, one coalesced atomic instruction per row ----
  {
    const int wave = tid >> 6;
    const int lane = tid & 63;     // = d
    #pragma unroll 4
    for (int rr = 0; rr < 32; ++rr) {
      const int row = wave * 32 + rr;
      const int code = bidx[row];
      atomicAdd(ws + W_UPD + (size_t)code * 64 + lane, z_lds[lane * 128 + row]);
    }
  }
}

// ---------------------------------------------------------------------------
// K3: EMA updates + normalization. Each block redundantly reduces n.
__global__ __launch_bounds__(256) void vq_final(const float* __restrict__ emb_ema,
                                                const float* __restrict__ counts_ema,
                                                const float* __restrict__ ws,
                                                float* __restrict__ out) {
  __shared__ float red[256];
  const int tid = threadIdx.x;
  const float* cnt = ws + W_CNT;

  float psum = 0.f;
  for (int t = tid; t < KCODES; t += 256) {
    const float ce  = counts_ema[t];
    const float cen = ce + 0.01f * (cnt[t] - ce);
    psum += cen;
    if (blockIdx.x == 0) out[O_CEN + t] = cen;
  }
  red[tid] = psum;
  __syncthreads();
  #pragma unroll
  for (int s = 128; s > 0; s >>= 1) {
    if (tid < s) red[tid] += red[tid + s];
    __syncthreads();
  }
  const float nsum = red[0];

  const int i = blockIdx.x * 256 + tid;   // 0..65535 over [D][K]
  const int d = i >> 10;
  const int k = i & 1023;

  const float ce  = counts_ema[k];
  const float cen = ce + 0.01f * (cnt[k] - ce);
  const float norm = (cen + 1e-5f) / (nsum + (float)KCODES * 1e-5f) * nsum;

  const float ema     = emb_ema[i];
  const float ema_new = ema + 0.01f * (ws[W_UPD + (size_t)k * 64 + d] - ema);
  out[O_EMA + i] = ema_new;
  out[O_EMB + i] = ema_new / norm;
}

// ---------------------------------------------------------------------------
extern "C" void kernel_launch(void* const* d_in, const int* in_sizes, int n_in,
                              void* d_out, int out_size, void* d_ws, size_t ws_size,
                              hipStream_t stream) {
  const float* z_e        = (const float*)d_in[0];
  const float* emb        = (const float*)d_in[1];
  const float* emb_ema    = (const float*)d_in[2];
  const float* counts_ema = (const float*)d_in[3];
  float* out = (float*)d_out;
  float* ws  = (float*)d_ws;

  // zero the accumulators (upd [K*D] + counts [K])
  hipMemsetAsync(ws, 0, (KCODES * DDIM + KCODES) * sizeof(float), stream);

  vq_prep<<<256, 256, 0, stream>>>(emb, ws);
  vq_main<<<512, 256, 0, stream>>>(z_e, emb, ws, out);
  vq_final<<<256, 256, 0, stream>>>(emb_ema, counts_ema, ws, out);
}